// Round 4
// baseline (17686.172 us; speedup 1.0000x reference)
//
#include <hip/hip_runtime.h>
#include <math.h>

__device__ __forceinline__ float sigmoidf_(float x) { return 1.0f / (1.0f + expf(-x)); }

#define NB 8  // batch

// summary conv3x3 (C -> C8), relu, write f32 into ws, layout (B, C8, S, S).
// 4 output channels per thread: share the 3x3 input window loads.
__global__ void k_summary(const float* __restrict__ x, const float* __restrict__ w,
                          const float* __restrict__ bias, float* __restrict__ ws,
                          int C, int C8, int S) {
  int idx = blockIdx.x * blockDim.x + threadIdx.x;
  int cq4 = C8 >> 2;
  int total = NB * cq4 * S * S;
  if (idx >= total) return;
  int px = idx % S; int t = idx / S;
  int py = t % S; t /= S;
  int cq = t % cq4; int b = t / cq4;
  int co = cq << 2;

  float a0 = bias[co];
  float a1 = bias[co + 1];
  float a2 = bias[co + 2];
  float a3 = bias[co + 3];

  int kylo = (py == 0) ? 1 : 0;
  int kyhi = (py == S - 1) ? 1 : 2;
  int kxlo = (px == 0) ? 1 : 0;
  int kxhi = (px == S - 1) ? 1 : 2;

  const float* xb = x + (size_t)b * C * S * S;
  const float* w0 = w + (size_t)co * C * 9;
  size_t wstride = (size_t)C * 9;  // one output channel of weights

  for (int ci = 0; ci < C; ci++) {
    const float* xc = xb + (size_t)ci * S * S;
    const float* wp = w0 + (size_t)ci * 9;
    for (int ky = kylo; ky <= kyhi; ky++) {
      const float* xr = xc + (py + ky - 1) * S + (px - 1);
      const float* wr = wp + ky * 3;
      for (int kx = kxlo; kx <= kxhi; kx++) {
        float v = xr[kx];
        a0 += v * wr[kx];
        a1 += v * wr[kx + wstride];
        a2 += v * wr[kx + 2 * wstride];
        a3 += v * wr[kx + 3 * wstride];
      }
    }
  }
  size_t o  = ((size_t)(b * C8 + co) * S + py) * S + px;
  size_t cs = (size_t)S * S;
  ws[o]          = fmaxf(a0, 0.f);
  ws[o + cs]     = fmaxf(a1, 0.f);
  ws[o + 2 * cs] = fmaxf(a2, 0.f);
  ws[o + 3 * cs] = fmaxf(a3, 0.f);
}

// spatial correlation (49 shifts) + leaky_relu(0.01), f32 into d_out corr section
__global__ void k_corr(const float* __restrict__ f1, const float* __restrict__ f2,
                       float* __restrict__ corr_out, int C, int S) {
  int idx = blockIdx.x * blockDim.x + threadIdx.x;
  int total = NB * 49 * S * S;
  if (idx >= total) return;
  int px = idx % S; int t = idx / S;
  int py = t % S; t /= S;
  int d = t % 49; int b = t / 49;
  int qy = py + d / 7 - 3;
  int qx = px + d % 7 - 3;

  float acc = 0.f;
  if (qy >= 0 && qy < S && qx >= 0 && qx < S) {
    const float* p1 = f1 + ((size_t)b * C * S + py) * S + px;
    const float* p2 = f2 + ((size_t)b * C * S + qy) * S + qx;
    size_t cs = (size_t)S * S;
    for (int ci = 0; ci < C; ci++) {
      acc += p1[(size_t)ci * cs] * p2[(size_t)ci * cs];
    }
  }
  float lr = (acc > 0.f) ? acc : 0.01f * acc;
  corr_out[idx] = lr;  // idx decomposes exactly as (B,49,S,S)
}

// LSTM conv3x3 (2*CH -> 4*CH) + gates. One thread computes all 4 gates for
// (b, j, y, x). Input channels come from three sources (no staging copy):
//   ci in [0, C8)    : summary, ws f32 (B, C8, S, S)
//   ci in [C8, CH)   : corr, d_out section f32 (B, 49, S, S)
//   ci in [CH, 2*CH) : h input f32 (B, CH, S, S)
__global__ void k_lstm(const float* __restrict__ ws, const float* __restrict__ corr,
                       const float* __restrict__ hin,
                       const float* __restrict__ lw, const float* __restrict__ lb,
                       const float* __restrict__ cprev,
                       float* __restrict__ hout, float* __restrict__ cout,
                       int C8, int CH, int S) {
  int idx = blockIdx.x * blockDim.x + threadIdx.x;
  int total = NB * CH * S * S;
  if (idx >= total) return;
  int px = idx % S; int t = idx / S;
  int py = t % S; t /= S;
  int j = t % CH; int b = t / CH;
  int CH2 = 2 * CH;

  float a0 = lb[j];
  float a1 = lb[j + CH];
  float a2 = lb[j + 2 * CH];
  float a3 = lb[j + 3 * CH];

  int kylo = (py == 0) ? 1 : 0;
  int kyhi = (py == S - 1) ? 1 : 2;
  int kxlo = (px == 0) ? 1 : 0;
  int kxhi = (px == S - 1) ? 1 : 2;

  size_t cs = (size_t)S * S;
  size_t wstride = (size_t)CH * CH2 * 9;  // one gate block (CH output channels)
  const float* w0 = lw + (size_t)j * CH2 * 9;

  // three source segments: {base pointer, channel count}
  const float* srcs[3];
  int          cnts[3];
  srcs[0] = ws   + (size_t)b * C8 * cs;   cnts[0] = C8;
  srcs[1] = corr + (size_t)b * 49 * cs;   cnts[1] = 49;
  srcs[2] = hin  + (size_t)b * CH * cs;   cnts[2] = CH;

  int ci = 0;
  for (int sseg = 0; sseg < 3; sseg++) {
    const float* sp = srcs[sseg];
    int cnt = cnts[sseg];
    for (int cc = 0; cc < cnt; cc++, ci++) {
      const float* ic = sp + (size_t)cc * cs;
      const float* wp = w0 + (size_t)ci * 9;
      for (int ky = kylo; ky <= kyhi; ky++) {
        const float* xr = ic + (py + ky - 1) * S + (px - 1);
        const float* wr = wp + ky * 3;
        for (int kx = kxlo; kx <= kxhi; kx++) {
          float v = xr[kx];
          a0 += v * wr[kx];
          a1 += v * wr[kx + wstride];
          a2 += v * wr[kx + 2 * wstride];
          a3 += v * wr[kx + 3 * wstride];
        }
      }
    }
  }
  float ig = sigmoidf_(a0);
  float fg = sigmoidf_(a1);
  float og = sigmoidf_(a2);
  float gg = tanhf(a3);
  float cn = fg * cprev[idx] + ig * gg;
  float hn = og * tanhf(cn);
  hout[idx] = hn;  // idx decomposes exactly as (B,CH,S,S)
  cout[idx] = cn;
}

extern "C" void kernel_launch(void* const* d_in, const int* in_sizes, int n_in,
                              void* d_out, int out_size, void* d_ws, size_t ws_size,
                              hipStream_t stream) {
  (void)in_sizes; (void)n_in; (void)out_size; (void)ws_size;
  static const int CINa[6] = {512, 1024, 512, 256, 256, 256};
  static const int Sa[6]   = {64, 32, 16, 8, 4, 2};
  static const int CHa[6]  = {113, 177, 113, 81, 81, 81};
  const int B = 8;

  // output layout: h0..h5, c0..c5, corr0..corr5 (flat, f32)
  size_t h_off[6], c_off[6], corr_off[6];
  size_t off = 0;
  for (int i = 0; i < 6; i++) { h_off[i] = off;    off += (size_t)B * CHa[i] * Sa[i] * Sa[i]; }
  for (int i = 0; i < 6; i++) { c_off[i] = off;    off += (size_t)B * CHa[i] * Sa[i] * Sa[i]; }
  for (int i = 0; i < 6; i++) { corr_off[i] = off; off += (size_t)B * 49 * Sa[i] * Sa[i]; }

  float* out = (float*)d_out;
  float* wsf = (float*)d_ws;  // summary staging (B, C8, S, S) f32, reused per level (max 8.4 MB)

  for (int i = 0; i < 6; i++) {
    const float* x  = (const float*)d_in[8 * i + 0];
    const float* xp = (const float*)d_in[8 * i + 1];
    const float* h  = (const float*)d_in[8 * i + 2];
    const float* c  = (const float*)d_in[8 * i + 3];
    const float* sw = (const float*)d_in[8 * i + 4];
    const float* sb = (const float*)d_in[8 * i + 5];
    const float* lw = (const float*)d_in[8 * i + 6];
    const float* lb = (const float*)d_in[8 * i + 7];
    int C = CINa[i], S = Sa[i], CH = CHa[i], C8 = C / 8;

    int n1 = B * (C8 / 4) * S * S;
    k_summary<<<dim3((n1 + 255) / 256), dim3(256), 0, stream>>>(
        x, sw, sb, wsf, C, C8, S);

    int n2 = B * 49 * S * S;
    k_corr<<<dim3((n2 + 255) / 256), dim3(256), 0, stream>>>(
        x, xp, out + corr_off[i], C, S);

    int n3 = B * CH * S * S;
    k_lstm<<<dim3((n3 + 255) / 256), dim3(256), 0, stream>>>(
        wsf, out + corr_off[i], h, lw, lb, c, out + h_off[i], out + c_off[i], C8, CH, S);
  }
}

// Round 5
// 3417.104 us; speedup vs baseline: 5.1758x; 5.1758x over previous
//
#include <hip/hip_runtime.h>
#include <hip/hip_bf16.h>
#include <math.h>

typedef __hip_bfloat16 bf16;
typedef short bf16x8 __attribute__((ext_vector_type(8)));
typedef float f32x4 __attribute__((ext_vector_type(4)));

__device__ __forceinline__ float sigmoidf_(float x) { return 1.0f / (1.0f + expf(-x)); }

#define NB 8  // batch

// ---------------- staging: NCHW f32 -> NHWC bf16 (padded border +1, padded channels) ----
// out layout: (B, S+2, S+2, Cpad), interior at [y+1][x+1], channel offset coff.
__global__ void k_nchw2nhwc(const float* __restrict__ in, bf16* __restrict__ out,
                            int C, int S, int Cpad, int coff) {
  __shared__ float tile[16][17];
  int Sp = S + 2;
  int xt = blockIdx.x;          // x tile
  int ct = blockIdx.y;          // c tile
  int by = blockIdx.z;          // b*S + y
  int b = by / S, y = by % S;
  int x0 = xt * 16, c0 = ct * 16;
  int tx = threadIdx.x & 15, tc = threadIdx.x >> 4;
  float v = 0.f;
  if (c0 + tc < C && x0 + tx < S)
    v = in[(((size_t)b * C + c0 + tc) * S + y) * S + x0 + tx];
  tile[tc][tx] = v;
  __syncthreads();
  int tcc = threadIdx.x & 15;   // channel within tile (fastest -> coalesced writes)
  int txx = threadIdx.x >> 4;   // x within tile
  if (c0 + tcc < C && x0 + txx < S)
    out[(((size_t)b * Sp + y + 1) * Sp + (x0 + txx + 1)) * Cpad + coff + c0 + tcc]
        = __float2bfloat16(tile[tcc][txx]);
}

// ---------------- weight re-layouts (pads written as zero) ---------------------------
// lstm weights (4CH, CH2, 3, 3) f32 -> Wt[kk][g][Jpad][Cpad] bf16
__global__ void k_wlstm(const float* __restrict__ w, bf16* __restrict__ wt,
                        int CH, int CH2, int Jpad, int Cpad) {
  int idx = blockIdx.x * blockDim.x + threadIdx.x;
  int total = 9 * 4 * Jpad * Cpad;
  if (idx >= total) return;
  int ci = idx % Cpad; int t = idx / Cpad;
  int j = t % Jpad; t /= Jpad;
  int g = t % 4; int kk = t / 4;
  float v = 0.f;
  if (j < CH && ci < CH2)
    v = w[((size_t)(g * CH + j) * CH2 + ci) * 9 + kk];
  wt[idx] = __float2bfloat16(v);
}

// summary weights (C8, C, 3, 3) f32 -> Ws[kk][Npad][Cpad] bf16
__global__ void k_wsum(const float* __restrict__ w, bf16* __restrict__ wt,
                       int C8, int C, int Npad, int Cpad) {
  int idx = blockIdx.x * blockDim.x + threadIdx.x;
  int total = 9 * Npad * Cpad;
  if (idx >= total) return;
  int ci = idx % Cpad; int t = idx / Cpad;
  int co = t % Npad; int kk = t / Npad;
  float v = 0.f;
  if (co < C8 && ci < C)
    v = w[((size_t)co * C + ci) * 9 + kk];
  wt[idx] = __float2bfloat16(v);
}

// ---------------- summary conv GEMM: wave computes 64m x 64n, relu, bf16 -> D ---------
__global__ void __launch_bounds__(64)
k_conv_gemm(const bf16* __restrict__ A,    // (B,Sp,Sp,CpadX) pad1
            const bf16* __restrict__ Wt,   // [kk][Npad][CpadX]
            const float* __restrict__ bias,
            bf16* __restrict__ D,          // (B,Sp,Sp,CpadL) pad1, channels [0,C8)
            int S, int lS, int CpadX, int CpadL, int C8, int Npad, int M) {
  int lane = threadIdx.x;
  int quad = lane >> 4, r = lane & 15;
  int mtile = blockIdx.x, ntile = blockIdx.y;
  int Sp = S + 2;
  size_t abase[4];
#pragma unroll
  for (int s = 0; s < 4; s++) {
    int m = mtile * 64 + s * 16 + r;
    if (m >= M) m = M - 1;
    int b = m >> (2 * lS);
    int rem = m & ((1 << (2 * lS)) - 1);
    int y = rem >> lS, x = rem & ((1 << lS) - 1);
    abase[s] = (((size_t)b * Sp + y) * Sp + x) * CpadX + quad * 8;
  }
  f32x4 acc[4][4] = {};
  int n0 = ntile * 64;
  int KB = CpadX >> 5;
  for (int kk = 0; kk < 9; kk++) {
    int ky = kk / 3, kx = kk % 3;
    size_t aoff = ((size_t)ky * Sp + kx) * CpadX;
    size_t wbase = ((size_t)kk * Npad + n0 + r) * CpadX + quad * 8;
    for (int cb = 0; cb < KB; cb++) {
      bf16x8 af[4], bfr[4];
#pragma unroll
      for (int s = 0; s < 4; s++)
        af[s] = *(const bf16x8*)(A + abase[s] + aoff + cb * 32);
#pragma unroll
      for (int t = 0; t < 4; t++)
        bfr[t] = *(const bf16x8*)(Wt + wbase + (size_t)t * 16 * CpadX + cb * 32);
#pragma unroll
      for (int s = 0; s < 4; s++)
#pragma unroll
        for (int t = 0; t < 4; t++)
          acc[s][t] = __builtin_amdgcn_mfma_f32_16x16x32_bf16(af[s], bfr[t], acc[s][t], 0, 0, 0);
    }
  }
#pragma unroll
  for (int s = 0; s < 4; s++) {
#pragma unroll
    for (int i = 0; i < 4; i++) {
      int m = mtile * 64 + s * 16 + quad * 4 + i;
      if (m >= M) continue;
      int b = m >> (2 * lS);
      int rem = m & ((1 << (2 * lS)) - 1);
      int y = rem >> lS, x = rem & ((1 << lS) - 1);
      size_t dbase = (((size_t)b * Sp + y + 1) * Sp + (x + 1)) * CpadL;
#pragma unroll
      for (int t = 0; t < 4; t++) {
        int co = n0 + t * 16 + r;
        if (co < C8) {
          float v = acc[s][t][i] + bias[co];
          D[dbase + co] = __float2bfloat16(fmaxf(v, 0.f));
        }
      }
    }
  }
}

// ---------------- LSTM conv GEMM: wave computes 64m x (16j x 4gates), fused gates -----
__global__ void __launch_bounds__(64)
k_lstm_gemm(const bf16* __restrict__ A,    // (B,Sp,Sp,CpadL) staged lstm_in
            const bf16* __restrict__ Wt,   // [kk][4][Jpad][CpadL]
            const float* __restrict__ lb,  // (4CH)
            const float* __restrict__ cprev,  // (B,CH,S,S) f32
            float* __restrict__ hout, float* __restrict__ cout,
            int S, int lS, int CpadL, int CH, int Jpad, int M) {
  int lane = threadIdx.x;
  int quad = lane >> 4, r = lane & 15;
  int mtile = blockIdx.x, jt = blockIdx.y;
  int j0 = jt * 16;
  int Sp = S + 2;
  size_t abase[4];
#pragma unroll
  for (int s = 0; s < 4; s++) {
    int m = mtile * 64 + s * 16 + r;
    if (m >= M) m = M - 1;
    int b = m >> (2 * lS);
    int rem = m & ((1 << (2 * lS)) - 1);
    int y = rem >> lS, x = rem & ((1 << lS) - 1);
    abase[s] = (((size_t)b * Sp + y) * Sp + x) * CpadL + quad * 8;
  }
  f32x4 acc[4][4] = {};  // [msub][gate]
  int KB = CpadL >> 5;
  for (int kk = 0; kk < 9; kk++) {
    int ky = kk / 3, kx = kk % 3;
    size_t aoff = ((size_t)ky * Sp + kx) * CpadL;
    size_t wbase = (((size_t)kk * 4) * Jpad + j0 + r) * CpadL + quad * 8;
    for (int cb = 0; cb < KB; cb++) {
      bf16x8 af[4], bfr[4];
#pragma unroll
      for (int s = 0; s < 4; s++)
        af[s] = *(const bf16x8*)(A + abase[s] + aoff + cb * 32);
#pragma unroll
      for (int g = 0; g < 4; g++)
        bfr[g] = *(const bf16x8*)(Wt + wbase + (size_t)g * Jpad * CpadL + cb * 32);
#pragma unroll
      for (int s = 0; s < 4; s++)
#pragma unroll
        for (int g = 0; g < 4; g++)
          acc[s][g] = __builtin_amdgcn_mfma_f32_16x16x32_bf16(af[s], bfr[g], acc[s][g], 0, 0, 0);
    }
  }
  int j = j0 + r;
  bool jok = (j < CH);
  float bi = jok ? lb[j] : 0.f;
  float bf_ = jok ? lb[CH + j] : 0.f;
  float bo = jok ? lb[2 * CH + j] : 0.f;
  float bg = jok ? lb[3 * CH + j] : 0.f;
  if (!jok) return;
#pragma unroll
  for (int s = 0; s < 4; s++) {
#pragma unroll
    for (int i = 0; i < 4; i++) {
      int m = mtile * 64 + s * 16 + quad * 4 + i;
      if (m >= M) continue;
      int b = m >> (2 * lS);
      int rem = m & ((1 << (2 * lS)) - 1);
      int y = rem >> lS, x = rem & ((1 << lS) - 1);
      size_t o = (((size_t)b * CH + j) * S + y) * S + x;
      float ig = sigmoidf_(acc[s][0][i] + bi);
      float fg = sigmoidf_(acc[s][1][i] + bf_);
      float og = sigmoidf_(acc[s][2][i] + bo);
      float gg = tanhf(acc[s][3][i] + bg);
      float cn = fg * cprev[o] + ig * gg;
      hout[o] = og * tanhf(cn);
      cout[o] = cn;
    }
  }
}

// ---------------- correlation: f32 exact to d_out, bf16 copy into staged D -----------
__global__ void k_corr(const float* __restrict__ f1, const float* __restrict__ f2,
                       float* __restrict__ corr_out, bf16* __restrict__ D,
                       int C, int S, int CpadL, int C8) {
  int idx = blockIdx.x * blockDim.x + threadIdx.x;
  int total = NB * 49 * S * S;
  if (idx >= total) return;
  int px = idx % S; int t = idx / S;
  int py = t % S; t /= S;
  int d = t % 49; int b = t / 49;
  int qy = py + d / 7 - 3;
  int qx = px + d % 7 - 3;

  float acc = 0.f;
  if (qy >= 0 && qy < S && qx >= 0 && qx < S) {
    const float* p1 = f1 + ((size_t)b * C * S + py) * S + px;
    const float* p2 = f2 + ((size_t)b * C * S + qy) * S + qx;
    size_t cs = (size_t)S * S;
    for (int ci = 0; ci < C; ci++) {
      acc += p1[(size_t)ci * cs] * p2[(size_t)ci * cs];
    }
  }
  float lr = (acc > 0.f) ? acc : 0.01f * acc;
  corr_out[idx] = lr;
  int Sp = S + 2;
  D[(((size_t)b * Sp + py + 1) * Sp + (px + 1)) * CpadL + C8 + d] = __float2bfloat16(lr);
}

extern "C" void kernel_launch(void* const* d_in, const int* in_sizes, int n_in,
                              void* d_out, int out_size, void* d_ws, size_t ws_size,
                              hipStream_t stream) {
  (void)in_sizes; (void)n_in; (void)out_size; (void)ws_size;
  static const int CINa[6] = {512, 1024, 512, 256, 256, 256};
  static const int Sa[6]   = {64, 32, 16, 8, 4, 2};
  static const int lSa[6]  = {6, 5, 4, 3, 2, 1};
  static const int CHa[6]  = {113, 177, 113, 81, 81, 81};
  static const int CpadLa[6] = {256, 384, 256, 192, 192, 192};  // 2*CH -> mult of 32
  static const int Jpada[6]  = {128, 192, 128, 96, 96, 96};     // CH -> mult of 16
  const int B = 8;

  size_t h_off[6], c_off[6], corr_off[6];
  size_t off = 0;
  for (int i = 0; i < 6; i++) { h_off[i] = off;    off += (size_t)B * CHa[i] * Sa[i] * Sa[i]; }
  for (int i = 0; i < 6; i++) { c_off[i] = off;    off += (size_t)B * CHa[i] * Sa[i] * Sa[i]; }
  for (int i = 0; i < 6; i++) { corr_off[i] = off; off += (size_t)B * 49 * Sa[i] * Sa[i]; }

  float* out = (float*)d_out;
  char* ws = (char*)d_ws;
  // arena: A (x NHWC pad1) 36MB | D (lstm_in NHWC pad1) 18MB | Wsum 3MB | Wlstm 6MB
  const size_t offA = 0;
  const size_t offD = 37748736;
  const size_t offWs = offD + 18874368;
  const size_t offWl = offWs + 3145728;

  for (int i = 0; i < 6; i++) {
    const float* x  = (const float*)d_in[8 * i + 0];
    const float* xp = (const float*)d_in[8 * i + 1];
    const float* h  = (const float*)d_in[8 * i + 2];
    const float* c  = (const float*)d_in[8 * i + 3];
    const float* sw = (const float*)d_in[8 * i + 4];
    const float* sb = (const float*)d_in[8 * i + 5];
    const float* lw = (const float*)d_in[8 * i + 6];
    const float* lb = (const float*)d_in[8 * i + 7];
    int C = CINa[i], S = Sa[i], lS = lSa[i], CH = CHa[i], C8 = C / 8;
    int CH2 = 2 * CH, CpadL = CpadLa[i], Jpad = Jpada[i];
    int Sp = S + 2;
    int Npad = (C8 + 63) / 64 * 64;
    int M = B * S * S;
    int Mtiles = (M + 63) / 64;

    bf16* Abuf = (bf16*)(ws + offA);
    bf16* Dbuf = (bf16*)(ws + offD);
    bf16* Wsum = (bf16*)(ws + offWs);
    bf16* Wlstm = (bf16*)(ws + offWl);

    size_t sizeA = (size_t)B * Sp * Sp * C * 2;
    size_t sizeD = (size_t)B * Sp * Sp * CpadL * 2;
    hipMemsetAsync(Abuf, 0, sizeA, stream);
    hipMemsetAsync(Dbuf, 0, sizeD, stream);

    // x -> A (NHWC bf16, pad1); CpadX == C (all multiples of 32)
    {
      dim3 g((S + 15) / 16, (C + 15) / 16, B * S);
      k_nchw2nhwc<<<g, 256, 0, stream>>>(x, Abuf, C, S, C, 0);
    }
    // summary weights
    {
      int tot = 9 * Npad * C;
      k_wsum<<<(tot + 255) / 256, 256, 0, stream>>>(sw, Wsum, C8, C, Npad, C);
    }
    // summary GEMM -> D channels [0, C8)
    {
      dim3 g(Mtiles, Npad / 64);
      k_conv_gemm<<<g, 64, 0, stream>>>(Abuf, Wsum, sb, Dbuf, S, lS, C, CpadL, C8, Npad, M);
    }
    // correlation -> d_out (f32) + D channels [C8, C8+49)
    {
      int tot = B * 49 * S * S;
      k_corr<<<(tot + 255) / 256, 256, 0, stream>>>(x, xp, out + corr_off[i], Dbuf,
                                                    C, S, CpadL, C8);
    }
    // h -> D channels [C8+49, 2CH)
    {
      dim3 g((S + 15) / 16, (CH + 15) / 16, B * S);
      k_nchw2nhwc<<<g, 256, 0, stream>>>(h, Dbuf, CH, S, CpadL, C8 + 49);
    }
    // lstm weights
    {
      int tot = 9 * 4 * Jpad * CpadL;
      k_wlstm<<<(tot + 255) / 256, 256, 0, stream>>>(lw, Wlstm, CH, CH2, Jpad, CpadL);
    }
    // LSTM GEMM + fused gates
    {
      dim3 g(Mtiles, Jpad / 16);
      k_lstm_gemm<<<g, 64, 0, stream>>>(Dbuf, Wlstm, lb, c,
                                        out + h_off[i], out + c_off[i],
                                        S, lS, CpadL, CH, Jpad, M);
    }
  }
}